// Round 1
// baseline (40809.967 us; speedup 1.0000x reference)
//
#include <hip/hip_runtime.h>
#include <hip/hip_bf16.h>
#include <math.h>

#define Bsz 256
#define Tn  512
#define En  512
#define Hn  1024
#define Cn  128
#define DECAY 0.9f

typedef unsigned short u16;
typedef unsigned int   u32;
typedef __attribute__((ext_vector_type(8))) short bf16x8;
typedef __attribute__((ext_vector_type(4))) float f32x4;

__device__ __forceinline__ u16 f2bf(float f) {
  union { float f; u32 u; } v; v.f = f;
  u32 x = v.u;
  return (u16)((x + 0x7fffu + ((x >> 16) & 1u)) >> 16);  // RNE
}

__device__ __forceinline__ u32 pk2(float a, float b) {
  float2 f2; f2.x = a; f2.y = b;
  __hip_bfloat162 h = __float22bfloat162_rn(f2);          // v_cvt_pk_bf16_f32
  union { __hip_bfloat162 h; u32 u; } v; v.h = h;
  return v.u;
}

// ---------------- prep kernels ----------------

// (fallback layout) Wc[4096][1536] = bf16([W_ih | W_hh]) row-major
__global__ void k_prep_wc(const float* __restrict__ Wih, const float* __restrict__ Whh,
                          u16* __restrict__ Wc) {
  int r = blockIdx.x;
  const float* sih = Wih + (size_t)r * En;
  const float* shh = Whh + (size_t)r * Hn;
  u16* dst = Wc + (size_t)r * (En + Hn);
  for (int k = threadIdx.x; k < En + Hn; k += 256) {
    float v = (k < En) ? sih[k] : shh[k - En];
    dst[k] = f2bf(v);
  }
}

// packed gate weights: Wp[jt 0..127][n 0..31][k 0..1535], n = g*8+jj <-> row g*1024+jt*8+jj
__global__ void k_prep_wp(const float* __restrict__ Wih, const float* __restrict__ Whh,
                          u16* __restrict__ Wp) {
  int p = blockIdx.x;            // 0..4095 packed row
  int jt = p >> 5, n = p & 31, g = n >> 3, jj = n & 7;
  int orig = g * 1024 + jt * 8 + jj;
  u16* dst = Wp + (size_t)p * 1536;
  for (int k = threadIdx.x; k < 1536; k += 256) {
    float v = (k < En) ? Wih[(size_t)orig * En + k] : Whh[(size_t)orig * Hn + (k - En)];
    dst[k] = f2bf(v);
  }
}

// Wl[512][1152] = bf16(W_lin)
__global__ void k_prep_wl(const float* __restrict__ Wlin, u16* __restrict__ Wl) {
  int e = blockIdx.x;
  for (int k = threadIdx.x; k < Hn + Cn; k += 256)
    Wl[(size_t)e * (Hn + Cn) + k] = f2bf(Wlin[(size_t)e * (Hn + Cn) + k]);
}

__global__ void k_prep_misc(const float* __restrict__ bih, const float* __restrict__ bhh,
                            const int* __restrict__ seq,
                            float* __restrict__ biasg, float* __restrict__ bgp,
                            int* __restrict__ nb, float* __restrict__ cst,
                            u16* __restrict__ hbuf, int* __restrict__ bar) {
  const int total = 4096 + 4096 + 512 + 2 + Bsz * Hn + 2 * Bsz * Hn;
  for (int i = blockIdx.x * 256 + threadIdx.x; i < total; i += gridDim.x * 256) {
    int j = i;
    if (j < 4096) { biasg[j] = bih[j] + bhh[j]; continue; }
    j -= 4096;
    if (j < 4096) {
      int g = (j & 31) >> 3, jj = j & 7, jt = j >> 5;
      int orig = g * 1024 + jt * 8 + jj;
      bgp[j] = bih[orig] + bhh[orig]; continue;
    }
    j -= 4096;
    if (j < 512) { int cnt = 0; for (int b = 0; b < Bsz; ++b) cnt += (seq[b] > j) ? 1 : 0; nb[j] = cnt; continue; }
    j -= 512;
    if (j < 2) { bar[j] = 0; continue; }
    j -= 2;
    if (j < Bsz * Hn) { cst[j] = 0.f; continue; }
    j -= Bsz * Hn;
    hbuf[j] = 0;
  }
}

// cate EMA scan along t -> ce bf16 [B][T][C]
__global__ void k_ema(const float* __restrict__ cate, u16* __restrict__ ce) {
  int b = blockIdx.x;
  int ch = threadIdx.x;
  float prev = 0.f;
  for (int t = 0; t < Tn; ++t) {
    float v = cate[((size_t)b * Tn + t) * Cn + ch];
    float eff = (t == 0) ? v : (DECAY * prev + (1.f - DECAY) * v);
    prev = eff;
    ce[((size_t)b * Tn + t) * Cn + ch] = f2bf(eff);
  }
}

__global__ void k_prefill(float* __restrict__ out, const float* __restrict__ blin) {
  size_t i = (size_t)blockIdx.x * 256 + threadIdx.x;
  int e = (int)((i * 4) & (En - 1));
  *(float4*)(out + i * 4) = *(const float4*)(blin + e);
}

// ---------------- fallback per-timestep kernel (previous proven path) ----------------
__global__ __launch_bounds__(256)
void k_step(int t,
            const float* __restrict__ x, const int* __restrict__ nb,
            const u16* __restrict__ Wc, const float* __restrict__ biasg,
            const u16* __restrict__ Wl, const float* __restrict__ blin,
            const u16* __restrict__ ce,
            float* __restrict__ cst, u16* __restrict__ hbuf,
            float* __restrict__ out) {
  __shared__ __align__(16) u16 As[32 * 40];
  __shared__ __align__(16) u16 Bs[4 * 32 * 40];
  __shared__ float gbuf[4 * 32 * 32];

  const int tid  = threadIdx.x;
  const int wave = tid >> 6, lane = tid & 63;
  const int nrow  = lane & 15;
  const int khalf = lane >> 4;
  const int kcol  = khalf * 8;
  const int ar = tid >> 3;
  const int ak = (tid & 7) * 4;
  const int bn = lane >> 1;
  const int bh = (lane & 1) * 16;

  if (blockIdx.x < 256) {
    if (t >= Tn) return;
    const int nbt = nb[t];
    const int bm = blockIdx.x >> 5, hn = blockIdx.x & 31;
    const int b0 = bm * 32, j0 = hn * 32;
    if (b0 >= nbt) return;

    const u16* __restrict__ hprev = hbuf + (size_t)(t & 1) * (Bsz * Hn);
    u16* __restrict__ hnext = hbuf + (size_t)((t + 1) & 1) * (Bsz * Hn);

    f32x4 acc[2][2] = {};
    const u16* wrow = Wc + (size_t)(wave * Hn + j0 + bn) * 1536;

    for (int kc = 0; kc < 48; ++kc) {
      const int k0 = kc * 32;
      {
        const int k = k0 + ak;
        const int b = b0 + ar;
        if (k < En) {
          const float4 v = *(const float4*)(x + ((size_t)b * Tn + t) * En + k);
          ushort4 s;
          s.x = f2bf(v.x); s.y = f2bf(v.y); s.z = f2bf(v.z); s.w = f2bf(v.w);
          *(ushort4*)(As + ar * 40 + ak) = s;
        } else {
          *(ushort4*)(As + ar * 40 + ak) =
              *(const ushort4*)(hprev + (size_t)b * Hn + (k - En));
        }
      }
      {
        const u16* p = wrow + k0 + bh;
        uint4 v0 = *(const uint4*)p;
        uint4 v1 = *(const uint4*)(p + 8);
        u16* q = Bs + (wave * 32 + bn) * 40 + bh;
        *(uint4*)q = v0;
        *(uint4*)(q + 8) = v1;
      }
      __syncthreads();
      bf16x8 a0  = *(const bf16x8*)(As + nrow * 40 + kcol);
      bf16x8 a1  = *(const bf16x8*)(As + (16 + nrow) * 40 + kcol);
      bf16x8 bb0 = *(const bf16x8*)(Bs + (wave * 32 + nrow) * 40 + kcol);
      bf16x8 bb1 = *(const bf16x8*)(Bs + (wave * 32 + 16 + nrow) * 40 + kcol);
      acc[0][0] = __builtin_amdgcn_mfma_f32_16x16x32_bf16(a0, bb0, acc[0][0], 0, 0, 0);
      acc[0][1] = __builtin_amdgcn_mfma_f32_16x16x32_bf16(a0, bb1, acc[0][1], 0, 0, 0);
      acc[1][0] = __builtin_amdgcn_mfma_f32_16x16x32_bf16(a1, bb0, acc[1][0], 0, 0, 0);
      acc[1][1] = __builtin_amdgcn_mfma_f32_16x16x32_bf16(a1, bb1, acc[1][1], 0, 0, 0);
      __syncthreads();
    }

    for (int mi = 0; mi < 2; ++mi)
      for (int ni = 0; ni < 2; ++ni) {
        const int n = ni * 16 + nrow;
        const float bg = biasg[wave * Hn + j0 + n];
        for (int r = 0; r < 4; ++r) {
          const int m = mi * 16 + khalf * 4 + r;
          gbuf[wave * 1024 + m * 32 + n] = acc[mi][ni][r] + bg;
        }
      }
    __syncthreads();

    for (int p = tid; p < 1024; p += 256) {
      const int m = p >> 5, n = p & 31;
      const int b = b0 + m, j = j0 + n;
      const float gi = gbuf[0 * 1024 + p];
      const float gf = gbuf[1 * 1024 + p];
      const float gg = gbuf[2 * 1024 + p];
      const float go = gbuf[3 * 1024 + p];
      const float si = 1.f / (1.f + __expf(-gi));
      const float sf = 1.f / (1.f + __expf(-gf));
      const float tg = tanhf(gg);
      const float so = 1.f / (1.f + __expf(-go));
      const size_t idx = (size_t)b * Hn + j;
      const float cn = sf * cst[idx] + si * tg;
      cst[idx] = cn;
      hnext[idx] = f2bf(so * tanhf(cn));
    }
  } else {
    if (t == 0) return;
    const int tl = t - 1;
    const int nbl = nb[tl];
    const int lid = blockIdx.x - 256;
    const int bm = lid >> 2, en = lid & 3;
    const int b0 = bm * 32, e0 = en * 128;
    if (b0 >= nbl) return;

    const u16* __restrict__ hcur = hbuf + (size_t)(t & 1) * (Bsz * Hn);

    f32x4 acc[2][2] = {};
    const u16* wrow = Wl + (size_t)(e0 + wave * 32 + bn) * 1152;

    for (int kc = 0; kc < 36; ++kc) {
      const int k0 = kc * 32;
      {
        const int k = k0 + ak;
        const int b = b0 + ar;
        const u16* src = (k < Hn)
            ? (hcur + (size_t)b * Hn + k)
            : (ce + ((size_t)b * Tn + tl) * Cn + (k - Hn));
        *(ushort4*)(As + ar * 40 + ak) = *(const ushort4*)src;
      }
      {
        const u16* p = wrow + k0 + bh;
        uint4 v0 = *(const uint4*)p;
        uint4 v1 = *(const uint4*)(p + 8);
        u16* q = Bs + (wave * 32 + bn) * 40 + bh;
        *(uint4*)q = v0;
        *(uint4*)(q + 8) = v1;
      }
      __syncthreads();
      bf16x8 a0  = *(const bf16x8*)(As + nrow * 40 + kcol);
      bf16x8 a1  = *(const bf16x8*)(As + (16 + nrow) * 40 + kcol);
      bf16x8 bb0 = *(const bf16x8*)(Bs + (wave * 32 + nrow) * 40 + kcol);
      bf16x8 bb1 = *(const bf16x8*)(Bs + (wave * 32 + 16 + nrow) * 40 + kcol);
      acc[0][0] = __builtin_amdgcn_mfma_f32_16x16x32_bf16(a0, bb0, acc[0][0], 0, 0, 0);
      acc[0][1] = __builtin_amdgcn_mfma_f32_16x16x32_bf16(a0, bb1, acc[0][1], 0, 0, 0);
      acc[1][0] = __builtin_amdgcn_mfma_f32_16x16x32_bf16(a1, bb0, acc[1][0], 0, 0, 0);
      acc[1][1] = __builtin_amdgcn_mfma_f32_16x16x32_bf16(a1, bb1, acc[1][1], 0, 0, 0);
      __syncthreads();
    }

    for (int mi = 0; mi < 2; ++mi)
      for (int ni = 0; ni < 2; ++ni) {
        const int e = e0 + wave * 32 + ni * 16 + nrow;
        const float bl = blin[e];
        for (int r = 0; r < 4; ++r) {
          const int b = b0 + mi * 16 + khalf * 4 + r;
          if (b < nbl)
            out[((size_t)b * Tn + tl) * En + e] = acc[mi][ni][r] + bl;
        }
      }
  }
}

// ---------------- persistent cooperative kernel ----------------
// LDS layout (bytes):
//   [0, 74240)        WlL  : resident W_lin slice [32 cols][1160] u16
//   [74240, 111104)   gA   : gate A staging, 2 bufs x [128][72] u16
//   [111104, 129792)  lA   : linear A staging [16][584] u16
//                     (overlays: gbuf f32[128][34] during gate cell;
//                                pacc f32[4][16][33] during linear reduce)
#define SMEM_BYTES 129792

__device__ __forceinline__ void gridbar(int* __restrict__ bar) {
  __syncthreads();
  if (threadIdx.x == 0) {
    int g = __hip_atomic_load(bar + 1, __ATOMIC_RELAXED, __HIP_MEMORY_SCOPE_AGENT);
    if (__hip_atomic_fetch_add(bar, 1, __ATOMIC_ACQ_REL, __HIP_MEMORY_SCOPE_AGENT) == 255) {
      __hip_atomic_store(bar, 0, __ATOMIC_RELAXED, __HIP_MEMORY_SCOPE_AGENT);
      __hip_atomic_fetch_add(bar + 1, 1, __ATOMIC_RELEASE, __HIP_MEMORY_SCOPE_AGENT);
    } else {
      while (__hip_atomic_load(bar + 1, __ATOMIC_ACQUIRE, __HIP_MEMORY_SCOPE_AGENT) == g)
        __builtin_amdgcn_s_sleep(1);
    }
  }
  __syncthreads();
}

__device__ __forceinline__ void load_f4x8(const float* __restrict__ src, float4* r) {
#pragma unroll
  for (int j = 0; j < 8; ++j) r[j] = *(const float4*)(src + j * 4);
}

__device__ __forceinline__ void pack_write(u16* __restrict__ dst, const float4* r) {
#pragma unroll
  for (int j2 = 0; j2 < 4; ++j2) {
    union { u32 u[4]; bf16x8 v; } p;
    p.u[0] = pk2(r[2 * j2].x,     r[2 * j2].y);
    p.u[1] = pk2(r[2 * j2].z,     r[2 * j2].w);
    p.u[2] = pk2(r[2 * j2 + 1].x, r[2 * j2 + 1].y);
    p.u[3] = pk2(r[2 * j2 + 1].z, r[2 * j2 + 1].w);
    *(bf16x8*)(dst + j2 * 8) = p.v;
  }
}

__global__ __launch_bounds__(256, 1)
void k_persist(const float* __restrict__ x, const int* __restrict__ nb,
               const u16* __restrict__ Wp, const float* __restrict__ bgp,
               const u16* __restrict__ Wl, const float* __restrict__ blin,
               const u16* __restrict__ ce, u16* __restrict__ hb,
               float* __restrict__ out, int* __restrict__ bar) {
  extern __shared__ char smem[];
  u16*   WlL  = (u16*)(smem);
  u16*   gA   = (u16*)(smem + 74240);
  u16*   lA   = (u16*)(smem + 111104);
  float* gbuf = (float*)(smem + 111104);
  float* pacc = (float*)(smem + 111104);

  const int tid  = threadIdx.x, blk = blockIdx.x;
  const int wave = tid >> 6, lane = tid & 63;
  const int nrow = lane & 15, kh = lane >> 4;
  const int wm = wave >> 1, wn = wave & 1;
  // gate mapping: block covers batch rows [b0, b0+128) x h-cols [jt*8, jt*8+8) (x4 gates)
  const int bm = blk >> 7, jt = blk & 127;
  const int b0 = bm * 128;
  // linear mapping: block covers batch rows [r0, r0+16) x out-cols [e0, e0+32)
  const int rt = blk >> 4, ct = blk & 15;
  const int r0 = rt * 16, e0 = ct * 32;
  // staging mapping
  const int srow = tid & 127, sseg = tid >> 7;
  // cell mapping
  const int crow = tid >> 1, jj0 = (tid & 1) * 4;

  // ---- init: resident W_lin slice -> LDS ----
  for (int i = tid; i < 4608; i += 256) {
    const int row = i & 31, g = i >> 5;   // 32 rows x 144 groups of 8
    *(bf16x8*)(WlL + row * 1160 + g * 8) =
        *(const bf16x8*)(Wl + (size_t)(e0 + row) * 1152 + g * 8);
  }

  // ---- init: resident gate-weight fragments -> VGPRs (192 per lane) ----
  bf16x8 wf[48];
  {
    const u16* wp = Wp + (size_t)(jt * 32 + wn * 16 + nrow) * 1536 + kh * 8;
#pragma unroll
    for (int c = 0; c < 48; ++c) wf[c] = *(const bf16x8*)(wp + c * 32);
  }
  const float bias_r = bgp[jt * 32 + wn * 16 + nrow];
  float creg[4] = {0.f, 0.f, 0.f, 0.f};   // persistent c-state

  float4 xr[8], xr2[8];
  bf16x8 hr[4];

  // ---- initial prestage for t=0: chunk0 (via xr2) + chunk1 loads (held in xr) ----
  {
    const float* s0 = x + (size_t)(b0 + srow) * (Tn * En) + sseg * 32;   // t=0
    load_f4x8(s0, xr2);
    load_f4x8(s0 + 64, xr);
    pack_write(gA + srow * 72 + sseg * 32, xr2);
  }
  __syncthreads();

  for (int t = 0; t < Tn; ++t) {
    const int nbt = nb[t];
    const int nbn = (t < Tn - 1) ? nb[t + 1] : 0;

    // ================= gate GEMM + cell =================
    if (b0 < nbt) {
      const u16* __restrict__ hprev = hb + (size_t)((t + 1) & 1) * (Bsz * Hn);
      f32x4 acc[4] = {};
#pragma unroll
      for (int kc = 0; kc < 24; ++kc) {
        // issue loads for chunk kc+1 (kc==0's chunk1 was preloaded pre-barrier)
        if (kc >= 1 && kc < 23) {
          if (kc + 1 < 8) {
            const float* src = x + ((size_t)(b0 + srow) * Tn + t) * En + (kc + 1) * 64 + sseg * 32;
            load_f4x8(src, xr);
          } else {
            const u16* src = hprev + (size_t)(b0 + srow) * Hn + (kc + 1 - 8) * 64 + sseg * 32;
#pragma unroll
            for (int j = 0; j < 4; ++j) hr[j] = *(const bf16x8*)(src + j * 8);
          }
        }
        // compute chunk kc (K=64 -> 2 sub-chunks of 32)
        {
          const u16* base = gA + (kc & 1) * 9216;
#pragma unroll
          for (int s = 0; s < 2; ++s) {
#pragma unroll
            for (int mf = 0; mf < 4; ++mf) {
              bf16x8 a = *(const bf16x8*)(base + (wm * 64 + mf * 16 + nrow) * 72 + s * 32 + kh * 8);
              acc[mf] = __builtin_amdgcn_mfma_f32_16x16x32_bf16(a, wf[2 * kc + s], acc[mf], 0, 0, 0);
            }
          }
        }
        // write chunk kc+1 into the other buffer
        if (kc < 23) {
          u16* dst = gA + ((kc + 1) & 1) * 9216 + srow * 72 + sseg * 32;
          if (kc + 1 < 8) {
            pack_write(dst, xr);
          } else {
#pragma unroll
            for (int j = 0; j < 4; ++j) *(bf16x8*)(dst + j * 8) = hr[j];
          }
        }
        __syncthreads();
      }

      // dump pre-activations (+bias) to gbuf[m][34]
#pragma unroll
      for (int mf = 0; mf < 4; ++mf)
#pragma unroll
        for (int r = 0; r < 4; ++r)
          gbuf[(wm * 64 + mf * 16 + kh * 4 + r) * 34 + wn * 16 + nrow] = acc[mf][r] + bias_r;
      __syncthreads();

      // cell update: thread handles (b0+crow, h-cols jt*8+jj0 .. +3)
      {
        const int b = b0 + crow;
        if (b < nbt) {
          const float* gr = gbuf + crow * 34 + jj0;
          ushort4 hv;
          u16 hvv[4];
#pragma unroll
          for (int r = 0; r < 4; ++r) {
            const float gi = gr[r], gf = gr[8 + r], gg = gr[16 + r], go = gr[24 + r];
            const float si = 1.f / (1.f + __expf(-gi));
            const float sf = 1.f / (1.f + __expf(-gf));
            const float tg = tanhf(gg);
            const float so = 1.f / (1.f + __expf(-go));
            const float cn = sf * creg[r] + si * tg;
            creg[r] = cn;
            hvv[r] = f2bf(so * tanhf(cn));
          }
          hv.x = hvv[0]; hv.y = hvv[1]; hv.z = hvv[2]; hv.w = hvv[3];
          *(ushort4*)(hb + (size_t)(t & 1) * (Bsz * Hn) + (size_t)b * Hn + jt * 8 + jj0) = hv;
        }
      }

      // prestage chunk0 of step t+1 (x only; no h dependency) + issue chunk1 loads
      if (t < Tn - 1 && b0 < nbn) {
        const float* s0 = x + ((size_t)(b0 + srow) * Tn + (t + 1)) * En + sseg * 32;
        load_f4x8(s0, xr2);
        load_f4x8(s0 + 64, xr);
        pack_write(gA + srow * 72 + sseg * 32, xr2);
      }
    }

    // ================= grid barrier: h_t visible everywhere =================
    gridbar(bar);

    // ================= output linear for step t =================
    if (r0 < nbt) {
      f32x4 lacc[2] = {};
      const u16* __restrict__ hcur = hb + (size_t)(t & 1) * (Bsz * Hn);
#pragma unroll
      for (int half = 0; half < 2; ++half) {
        // stage [16 rows][576 k] of [h_t | ce_t]
        for (int i = tid; i < 1152; i += 256) {
          const int row = i & 15, g = i >> 4;
          const int k = half * 576 + g * 8;
          const u16* src = (k < Hn)
              ? (hcur + (size_t)(r0 + row) * Hn + k)
              : (ce + ((size_t)(r0 + row) * Tn + t) * Cn + (k - Hn));
          *(bf16x8*)(lA + row * 584 + g * 8) = *(const bf16x8*)src;
        }
        __syncthreads();
        // K-split across the 4 waves (chunk c of 64 k goes to wave c%4)
#pragma unroll
        for (int c9 = 0; c9 < 9; ++c9) {
          const int c = half * 9 + c9;
          if ((c & 3) == wave) {
#pragma unroll
            for (int s = 0; s < 2; ++s) {
              bf16x8 a = *(const bf16x8*)(lA + nrow * 584 + c9 * 64 + s * 32 + kh * 8);
#pragma unroll
              for (int nf = 0; nf < 2; ++nf) {
                bf16x8 b = *(const bf16x8*)(WlL + (nf * 16 + nrow) * 1160 + c * 64 + s * 32 + kh * 8);
                lacc[nf] = __builtin_amdgcn_mfma_f32_16x16x32_bf16(a, b, lacc[nf], 0, 0, 0);
              }
            }
          }
        }
        __syncthreads();
      }
      // dump per-wave partials, reduce, add bias, store
#pragma unroll
      for (int nf = 0; nf < 2; ++nf)
#pragma unroll
        for (int r = 0; r < 4; ++r)
          pacc[wave * 528 + (kh * 4 + r) * 33 + nf * 16 + nrow] = lacc[nf][r];
      __syncthreads();
#pragma unroll
      for (int ii = 0; ii < 2; ++ii) {
        const int idx = tid * 2 + ii;
        const int m = idx >> 5, n = idx & 31;
        if (r0 + m < nbt) {
          float v = pacc[m * 33 + n] + pacc[528 + m * 33 + n]
                  + pacc[1056 + m * 33 + n] + pacc[1584 + m * 33 + n]
                  + blin[e0 + n];
          out[((size_t)(r0 + m) * Tn + t) * En + e0 + n] = v;
        }
      }
    }
  }
}

// ---------------- launch ----------------
extern "C" void kernel_launch(void* const* d_in, const int* in_sizes, int n_in,
                              void* d_out, int out_size, void* d_ws, size_t ws_size,
                              hipStream_t stream) {
  const float* x    = (const float*)d_in[0];
  const float* cate = (const float*)d_in[1];
  const int*   seq  = (const int*)d_in[2];
  const float* Wih  = (const float*)d_in[3];
  const float* Whh  = (const float*)d_in[4];
  const float* bih  = (const float*)d_in[5];
  const float* bhh  = (const float*)d_in[6];
  const float* Wlin = (const float*)d_in[7];
  const float* blin = (const float*)d_in[8];
  float* out = (float*)d_out;

  char* w = (char*)d_ws;
  u16*   Wc    = (u16*)w;   w += (size_t)4096 * 1536 * 2;   // 12.58 MB (fallback)
  u16*   Wp    = (u16*)w;   w += (size_t)4096 * 1536 * 2;   // 12.58 MB (packed)
  u16*   Wl    = (u16*)w;   w += (size_t)512 * 1152 * 2;    //  1.18 MB
  float* biasg = (float*)w; w += (size_t)4096 * 4;          // fallback bias
  float* bgp   = (float*)w; w += (size_t)4096 * 4;          // packed bias
  int*   nb    = (int*)w;   w += (size_t)512 * 4;
  int*   bar   = (int*)w;   w += (size_t)64;                // grid barrier state
  u16*   ce    = (u16*)w;   w += (size_t)Bsz * Tn * Cn * 2; // 33.55 MB
  float* cst   = (float*)w; w += (size_t)Bsz * Hn * 4;      // fallback c-state
  u16*   hb    = (u16*)w;   w += (size_t)2 * Bsz * Hn * 2;
  (void)ws_size; (void)in_sizes; (void)n_in; (void)out_size;

  k_prep_wc<<<4096, 256, 0, stream>>>(Wih, Whh, Wc);
  k_prep_wp<<<4096, 256, 0, stream>>>(Wih, Whh, Wp);
  k_prep_wl<<<512, 256, 0, stream>>>(Wlin, Wl);
  k_prep_misc<<<3107, 256, 0, stream>>>(bih, bhh, seq, biasg, bgp, nb, cst, hb, bar);
  k_ema<<<256, 128, 0, stream>>>(cate, ce);
  k_prefill<<<65536, 256, 0, stream>>>(out, blin);

  static int attr_done = 0;
  if (!attr_done) {
    (void)hipFuncSetAttribute((const void*)k_persist,
                              hipFuncAttributeMaxDynamicSharedMemorySize, SMEM_BYTES);
    attr_done = 1;
  }

  void* kargs[] = {(void*)&x, (void*)&nb, (void*)&Wp, (void*)&bgp, (void*)&Wl,
                   (void*)&blin, (void*)&ce, (void*)&hb, (void*)&out, (void*)&bar};
  hipError_t err = hipLaunchCooperativeKernel((const void*)k_persist, dim3(256), dim3(256),
                                              kargs, (unsigned int)SMEM_BYTES, stream);
  if (err != hipSuccess) {
    // fallback: proven per-timestep path
    for (int t = 0; t <= Tn; ++t)
      k_step<<<288, 256, 0, stream>>>(t, x, nb, Wc, biasg, Wl, blin, ce, cst, hb, out);
  }
}